// Round 1
// baseline (236.387 us; speedup 1.0000x reference)
//
#include <hip/hip_runtime.h>

#define Bv 256
#define Tv 200
#define Cv 40
#define H1v 512
#define H2v 256
#define Ov 12
#define THv 1.0f

// ---------------------------------------------------------------------------
// Tiled transpose: out[C][R] = in[R][C]^T. Only needed for the (rare) spike
// gather path so those reads are coalesced. Dims here are multiples of 32.
// ---------------------------------------------------------------------------
__global__ void transpose_k(const float* __restrict__ in, float* __restrict__ out,
                            int R, int C)
{
    __shared__ float tile[32][33];
    const int bx = blockIdx.x * 32;   // col base in input
    const int by = blockIdx.y * 32;   // row base in input
    int x = bx + threadIdx.x;
    for (int i = threadIdx.y; i < 32; i += 8) {
        int y = by + i;
        if (y < R && x < C) tile[i][threadIdx.x] = in[y * C + x];
    }
    __syncthreads();
    x = by + threadIdx.x;             // output col = input row
    for (int i = threadIdx.y; i < 32; i += 8) {
        int y = bx + i;               // output row = input col
        if (y < C && x < R) out[y * R + x] = tile[threadIdx.x][i];
    }
}

// ---------------------------------------------------------------------------
// Main sequential SNN kernel: one block per batch element, 512 threads.
// thread tid < 512  -> owns hidden unit tid of layer 1
// thread tid < 256  -> additionally owns hidden unit tid of layer 2
// thread tid < 12   -> additionally owns output unit tid
// Spike vectors cross threads via 64-bit ballot masks in LDS (double-buffered
// by timestep parity). "any spike" flags let the zero-spike fast path skip
// all gather work.
// ---------------------------------------------------------------------------
__global__ __launch_bounds__(512) void snn_main(
    const float* __restrict__ x,
    const float* __restrict__ W1,
    const float* __restrict__ Wrec,
    const float* __restrict__ W2,
    const float* __restrict__ Wout,
    const float* __restrict__ alpha1, const float* __restrict__ rho1, const float* __restrict__ ba1,
    const float* __restrict__ alpha2, const float* __restrict__ rho2, const float* __restrict__ ba2,
    const float* __restrict__ beta_out,
    float* __restrict__ out,
    const float* __restrict__ wrecT, const float* __restrict__ w2T, int use_t)
{
    __shared__ unsigned long long s_m1[2][8];   // layer-1 spike masks (512 bits)
    __shared__ unsigned long long s_m2[2][4];   // layer-2 spike masks (256 bits)
    __shared__ int s_any1[2];
    __shared__ int s_any2[2];

    const int b    = blockIdx.x;
    const int tid  = threadIdx.x;
    const int lane = tid & 63;

    // --- per-thread W1 row in registers (40 floats = 10 float4) ---
    float4 w1r[10];
    {
        const float4* p = (const float4*)(W1 + tid * Cv);
        #pragma unroll
        for (int i = 0; i < 10; ++i) w1r[i] = p[i];
    }
    const float al1 = alpha1[tid], rh1 = rho1[tid], bb1 = ba1[tid];
    float v1 = 0.f, a1 = 0.f, spk1 = 0.f;
    float al2 = 0.f, rh2 = 0.f, bb2 = 0.f, v2 = 0.f, a2 = 0.f;
    if (tid < H2v) { al2 = alpha2[tid]; rh2 = rho2[tid]; bb2 = ba2[tid]; }
    const float beta = beta_out[0];
    float vout = 0.f, osum = 0.f;

    const float* xb = x + (size_t)b * (Tv * Cv);

    // --- pre-touch this block's x slice so the T-loop reads hit L2 ---
    float dummy = 0.f;
    for (int i = tid; i < Tv * Cv; i += 512) dummy += xb[i];
    asm volatile("" :: "v"(dummy));

    if (tid < 8) { s_m1[0][tid] = 0ull; s_m1[1][tid] = 0ull; }
    if (tid < 4) { s_m2[0][tid] = 0ull; s_m2[1][tid] = 0ull; }
    if (tid == 0) { s_any1[0] = 0; s_any1[1] = 0; s_any2[0] = 0; s_any2[1] = 0; }
    __syncthreads();

    for (int t = 0; t < Tv; ++t) {
        const int cur = t & 1, prev = cur ^ 1;

        // ================= phase 2: layer-1 input + update =================
        const float* xr = xb + t * Cv;           // block-uniform address
        float acc = 0.f;
        #pragma unroll
        for (int i = 0; i < 10; ++i) {
            const float4 xv = ((const float4*)xr)[i];
            acc += xv.x * w1r[i].x + xv.y * w1r[i].y
                 + xv.z * w1r[i].z + xv.w * w1r[i].w;
        }
        // recurrent term: gather Wrec columns of previous step's spikes
        if (s_any1[prev]) {
            #pragma unroll
            for (int w = 0; w < 8; ++w) {
                unsigned long long m = s_m1[prev][w];
                while (m) {
                    const int j = (w << 6) + __builtin_ctzll(m);
                    m &= (m - 1);
                    acc += use_t ? wrecT[j * H1v + tid] : Wrec[tid * H1v + j];
                }
            }
        }
        // ---- merged phase 5 (output layer) for step t-1 ----
        if (tid < Ov && t > 0) {
            float io = 0.f;
            if (s_any2[prev]) {
                for (int w = 0; w < 4; ++w) {
                    unsigned long long m = s_m2[prev][w];
                    while (m) {
                        const int j = (w << 6) + __builtin_ctzll(m);
                        m &= (m - 1);
                        io += Wout[tid * H2v + j];
                    }
                }
            }
            vout = beta * vout + (1.f - beta) * io;
            osum += vout;
        }
        // prepare s_any2 slot for this step's phase-4 writes (slot `cur`;
        // phase-5 above reads slot `prev` -> no race)
        if (tid == 511) s_any2[cur] = 0;

        // layer-1 state update
        v1 = al1 * (v1 - spk1 * THv) + (1.f - al1) * (acc - a1);
        const bool sp = (v1 >= THv);
        spk1 = sp ? 1.f : 0.f;
        a1 = rh1 * a1 + bb1 * spk1;
        const unsigned long long bal = __ballot(sp);
        if (lane == 0) {
            s_m1[cur][tid >> 6] = bal;
            if (bal) s_any1[cur] = 1;
        }
        __syncthreads();

        // ================= phase 4: layer-2 update =================
        if (tid < H2v) {
            float acc2 = 0.f;
            if (s_any1[cur]) {
                #pragma unroll
                for (int w = 0; w < 8; ++w) {
                    unsigned long long m = s_m1[cur][w];
                    while (m) {
                        const int j = (w << 6) + __builtin_ctzll(m);
                        m &= (m - 1);
                        acc2 += use_t ? w2T[j * H2v + tid] : W2[tid * H1v + j];
                    }
                }
            }
            v2 = al2 * v2 + (1.f - al2) * (acc2 - a2);
            const bool sp2 = (v2 >= THv);
            a2 = rh2 * a2 + bb2 * (sp2 ? 1.f : 0.f);
            const unsigned long long bal2 = __ballot(sp2);
            if (lane == 0) {
                s_m2[cur][tid >> 6] = bal2;
                if (bal2) s_any2[cur] = 1;
            }
        } else if (tid == 511) {
            // prepare s_any1 slot for next step's phase-2 writes (slot `prev`
            // = next step's `cur`; phase-4 reads slot `cur` -> no race)
            s_any1[prev] = 0;
        }
        __syncthreads();
    }

    // final phase 5 for t = T-1
    if (tid < Ov) {
        const int last = (Tv - 1) & 1;
        float io = 0.f;
        if (s_any2[last]) {
            for (int w = 0; w < 4; ++w) {
                unsigned long long m = s_m2[last][w];
                while (m) {
                    const int j = (w << 6) + __builtin_ctzll(m);
                    m &= (m - 1);
                    io += Wout[tid * H2v + j];
                }
            }
        }
        vout = beta * vout + (1.f - beta) * io;
        osum += vout;
        out[b * Ov + tid] = osum / (float)Tv;
    }
}

extern "C" void kernel_launch(void* const* d_in, const int* in_sizes, int n_in,
                              void* d_out, int out_size, void* d_ws, size_t ws_size,
                              hipStream_t stream)
{
    const float* x       = (const float*)d_in[0];
    const float* W1      = (const float*)d_in[1];
    const float* Wrec    = (const float*)d_in[2];
    const float* W2      = (const float*)d_in[3];
    const float* Wout    = (const float*)d_in[4];
    const float* alpha1  = (const float*)d_in[5];
    const float* rho1    = (const float*)d_in[6];
    const float* ba1     = (const float*)d_in[7];
    const float* alpha2  = (const float*)d_in[8];
    const float* rho2    = (const float*)d_in[9];
    const float* ba2     = (const float*)d_in[10];
    const float* beta_o  = (const float*)d_in[11];
    float* out = (float*)d_out;

    const size_t need = (size_t)(H1v * H1v + H1v * H2v) * sizeof(float);
    float* wrecT = (float*)d_ws;
    float* w2T   = wrecT + (size_t)H1v * H1v;
    const int use_t = (d_ws != nullptr && ws_size >= need) ? 1 : 0;

    if (use_t) {
        transpose_k<<<dim3(16, 16), dim3(32, 8), 0, stream>>>(Wrec, wrecT, H1v, H1v);
        transpose_k<<<dim3(16, 8),  dim3(32, 8), 0, stream>>>(W2,   w2T,   H2v, H1v);
    }
    snn_main<<<dim3(Bv), dim3(512), 0, stream>>>(
        x, W1, Wrec, W2, Wout,
        alpha1, rho1, ba1, alpha2, rho2, ba2, beta_o,
        out, wrecT, w2T, use_t);
}

// Round 2
// 206.325 us; speedup vs baseline: 1.1457x; 1.1457x over previous
//
#include <hip/hip_runtime.h>

#define Bv 256
#define Tv 200
#define Cv 40
#define H1v 512
#define H2v 256
#define Ov 12
#define THv 1.0f

typedef unsigned long long u64;

// ---------------------------------------------------------------------------
// One block per batch element, 512 threads (8 waves).
//   tid < 512 : owns layer-1 hidden unit `tid`
//   tid < 256 : also owns layer-2 hidden unit `tid`
//   tid < 12  : also owns output unit `tid`
//
// Software-pipelined, ONE barrier per step:
//   iteration t computes  L1(t)   [reads spk1(t-1) mask, slot prev]
//                         L2(t-1) [reads spk1(t-1) mask, slot prev]
//                         Out(t-2)[reads spk2(t-2) mask, slot prev]
//   and writes spk1(t) -> s_m1[cur], spk2(t-1) -> s_m2[cur].
// All reads hit slot `prev`, all writes hit slot `cur`; the single end-of-
// iteration barrier keeps every wave inside the same iteration, so the
// double buffer is race-free. Loop runs T+2 iterations (2 drain steps).
//
// x for the block (200x40 fp32 = 32 KB) is staged in LDS once; per-step
// reads are same-address broadcasts (conflict-free ds_read_b128).
// Spike vectors cross waves as ballot masks in LDS; the all-zero fast path
// (always taken on this data: absmax == 0) costs only an OR-reduce of the
// mask registers.
// ---------------------------------------------------------------------------
__global__ __launch_bounds__(512) void snn_main(
    const float* __restrict__ x,
    const float* __restrict__ W1,
    const float* __restrict__ Wrec,
    const float* __restrict__ W2,
    const float* __restrict__ Wout,
    const float* __restrict__ alpha1, const float* __restrict__ rho1, const float* __restrict__ ba1,
    const float* __restrict__ alpha2, const float* __restrict__ rho2, const float* __restrict__ ba2,
    const float* __restrict__ beta_out,
    float* __restrict__ out)
{
    __shared__ __align__(16) float lds_x[Tv * Cv];     // 32000 B
    __shared__ __align__(16) u64 s_m1[2][8];           // spk1 masks, 512 bits
    __shared__ __align__(16) u64 s_m2[2][4];           // spk2 masks, 256 bits

    const int b    = blockIdx.x;
    const int tid  = threadIdx.x;
    const int lane = tid & 63;

    // --- per-thread W1 row in registers (40 floats = 10 float4) ---
    float4 w1r[10];
    {
        const float4* p = (const float4*)(W1 + tid * Cv);
        #pragma unroll
        for (int i = 0; i < 10; ++i) w1r[i] = p[i];
    }
    const float al1 = alpha1[tid], rh1 = rho1[tid], bb1 = ba1[tid];
    float v1 = 0.f, a1 = 0.f, spk1 = 0.f;
    float al2 = 0.f, rh2 = 0.f, bb2 = 0.f, v2 = 0.f, a2 = 0.f;
    if (tid < H2v) { al2 = alpha2[tid]; rh2 = rho2[tid]; bb2 = ba2[tid]; }
    const float beta = beta_out[0];
    float vout = 0.f, osum = 0.f;

    // --- stage this block's x slice into LDS (coalesced float4) ---
    {
        const float4* xg = (const float4*)(x + (size_t)b * (Tv * Cv));
        float4* xl = (float4*)lds_x;
        for (int i = tid; i < (Tv * Cv) / 4; i += 512) xl[i] = xg[i];
    }
    if (tid < 8) { s_m1[0][tid] = 0ull; s_m1[1][tid] = 0ull; }
    if (tid < 4) { s_m2[0][tid] = 0ull; s_m2[1][tid] = 0ull; }
    __syncthreads();

    for (int t = 0; t < Tv + 2; ++t) {
        const int cur = t & 1, prev = cur ^ 1;

        // ---- read prev-step spike masks (broadcast LDS reads, issued early
        //      so latency overlaps the dot product below) ----
        u64 m1[8];
        #pragma unroll
        for (int i = 0; i < 8; ++i) m1[i] = s_m1[prev][i];
        u64 anyw = 0;
        #pragma unroll
        for (int i = 0; i < 8; ++i) anyw |= m1[i];
        const bool any1 = (anyw != 0ull);

        const bool doOut = (tid < Ov) & (t >= 2);
        u64 m2[4] = {0ull, 0ull, 0ull, 0ull};
        if (doOut) {
            #pragma unroll
            for (int i = 0; i < 4; ++i) m2[i] = s_m2[prev][i];
        }

        // ================= L1 update for step t =================
        if (t < Tv) {
            const float4* xr = (const float4*)(&lds_x[t * Cv]);
            float c0 = 0.f, c1 = 0.f, c2 = 0.f, c3 = 0.f;
            #pragma unroll
            for (int i = 0; i < 10; ++i) {
                const float4 xv = xr[i];
                c0 += xv.x * w1r[i].x;
                c1 += xv.y * w1r[i].y;
                c2 += xv.z * w1r[i].z;
                c3 += xv.w * w1r[i].w;
            }
            float acc = (c0 + c1) + (c2 + c3);
            if (any1) {            // recurrent gather (cold path; never on this data)
                #pragma unroll
                for (int w = 0; w < 8; ++w) {
                    u64 m = m1[w];
                    while (m) {
                        const int j = (w << 6) + __builtin_ctzll(m);
                        m &= (m - 1);
                        acc += Wrec[tid * H1v + j];
                    }
                }
            }
            v1 = al1 * (v1 - spk1 * THv) + (1.f - al1) * (acc - a1);
            const bool sp = (v1 >= THv);
            spk1 = sp ? 1.f : 0.f;
            a1 = rh1 * a1 + bb1 * spk1;
            const u64 bal = __ballot(sp);
            if (lane == 0) s_m1[cur][tid >> 6] = bal;
        }

        // ================= L2 update for step t-1 =================
        if ((tid < H2v) & (t >= 1) & (t <= Tv)) {
            float acc2 = 0.f;
            if (any1) {            // cold path
                #pragma unroll
                for (int w = 0; w < 8; ++w) {
                    u64 m = m1[w];
                    while (m) {
                        const int j = (w << 6) + __builtin_ctzll(m);
                        m &= (m - 1);
                        acc2 += W2[tid * H1v + j];
                    }
                }
            }
            v2 = al2 * v2 + (1.f - al2) * (acc2 - a2);
            const bool sp2 = (v2 >= THv);
            a2 = rh2 * a2 + bb2 * (sp2 ? 1.f : 0.f);
            const u64 bal2 = __ballot(sp2);
            if (lane == 0) s_m2[cur][tid >> 6] = bal2;
        }

        // ================= Out update for step t-2 =================
        if (doOut) {
            float io = 0.f;
            if (m2[0] | m2[1] | m2[2] | m2[3]) {   // cold path
                #pragma unroll
                for (int w = 0; w < 4; ++w) {
                    u64 m = m2[w];
                    while (m) {
                        const int j = (w << 6) + __builtin_ctzll(m);
                        m &= (m - 1);
                        io += Wout[tid * H2v + j];
                    }
                }
            }
            vout = beta * vout + (1.f - beta) * io;
            osum += vout;
        }

        __syncthreads();
    }

    if (tid < Ov) out[b * Ov + tid] = osum / (float)Tv;
}

extern "C" void kernel_launch(void* const* d_in, const int* in_sizes, int n_in,
                              void* d_out, int out_size, void* d_ws, size_t ws_size,
                              hipStream_t stream)
{
    const float* x       = (const float*)d_in[0];
    const float* W1      = (const float*)d_in[1];
    const float* Wrec    = (const float*)d_in[2];
    const float* W2      = (const float*)d_in[3];
    const float* Wout    = (const float*)d_in[4];
    const float* alpha1  = (const float*)d_in[5];
    const float* rho1    = (const float*)d_in[6];
    const float* ba1     = (const float*)d_in[7];
    const float* alpha2  = (const float*)d_in[8];
    const float* rho2    = (const float*)d_in[9];
    const float* ba2     = (const float*)d_in[10];
    const float* beta_o  = (const float*)d_in[11];
    float* out = (float*)d_out;

    snn_main<<<dim3(Bv), dim3(512), 0, stream>>>(
        x, W1, Wrec, W2, Wout,
        alpha1, rho1, ba1, alpha2, rho2, ba2, beta_o, out);
}